// Round 4
// baseline (714.052 us; speedup 1.0000x reference)
//
#include <hip/hip_runtime.h>

#define DD 128
#define TILE_E 64

typedef __attribute__((ext_vector_type(8))) short short8;
typedef __attribute__((ext_vector_type(4))) float f32x4;

__device__ __forceinline__ unsigned short f2bf(float f) {
  unsigned int u = __float_as_uint(f);
  u += 0x7FFF + ((u >> 16) & 1);   // RNE
  return (unsigned short)(u >> 16);
}

// ---- Phase A: build dest-sorted edge list (replaces 64M fp32 atomics) ----

__global__ __launch_bounds__(256) void hist_kernel(
    const int* __restrict__ eidx, int* __restrict__ cnt, int E) {
  int e = blockIdx.x * 256 + threadIdx.x;
  if (e < E) atomicAdd(&cnt[eidx[E + e]], 1);
}

// single-block exclusive scan over V counts -> off, and copy -> cur
__global__ __launch_bounds__(1024) void scan_kernel(
    const int* __restrict__ cnt, int* __restrict__ off, int* __restrict__ cur, int V) {
  __shared__ int s[1024];
  const int t = threadIdx.x;
  const int chunk = (V + 1023) / 1024;
  const int lo = t * chunk, hi = min(lo + chunk, V);
  int tot = 0;
  for (int v = lo; v < hi; ++v) tot += cnt[v];
  s[t] = tot;
  __syncthreads();
  // Hillis-Steele inclusive scan of thread totals
  for (int d = 1; d < 1024; d <<= 1) {
    int x = (t >= d) ? s[t - d] : 0;
    __syncthreads();
    s[t] += x;
    __syncthreads();
  }
  int run = (t > 0) ? s[t - 1] : 0;
  for (int v = lo; v < hi; ++v) {
    off[v] = run; cur[v] = run;
    run += cnt[v];
  }
}

__global__ __launch_bounds__(256) void fill_kernel(
    const int* __restrict__ eidx, int* __restrict__ cur,
    int* __restrict__ elist, int E) {
  int e = blockIdx.x * 256 + threadIdx.x;
  if (e < E) {
    int p = atomicAdd(&cur[eidx[E + e]], 1);
    elist[p] = e;
  }
}

// ---- Phase B: nm[v,:] = sum_{e: dest[e]=v} relu(ef[e,:])  (one wave per node) ----
// Fixed 16-row masked burst: 8 asm global_load_dwordx4 (half-wave per row, 2
// rows/instr) issued back-to-back; invalid slots read a safe row (L1 broadcast)
// and are zeroed in the accumulate. Forces 8 row-loads in flight per wave
// regardless of node degree (mean deg ~10 defeated the unrolled-loop version).
__global__ __launch_bounds__(256) void gather_sum_kernel(
    const float* __restrict__ ef, const int* __restrict__ off,
    const int* __restrict__ cnt, const int* __restrict__ elist,
    float* __restrict__ nm, int V) {
  const int lane = threadIdx.x & 63;
  const int half = lane >> 5;        // 0: even slots, 1: odd slots
  const int l32  = lane & 31;        // float4 index within row
  const int v = blockIdx.x * 4 + (threadIdx.x >> 6);
  if (v >= V) return;
  const int base = off[v];
  const int deg  = cnt[v];
  f32x4 acc = (f32x4){0.f, 0.f, 0.f, 0.f};
  if (deg > 0) {
    const int esafe = elist[base];
    for (int j = 0; j < deg; j += 16) {
      int idx[8];
      #pragma unroll
      for (int i = 0; i < 8; ++i) {
        int sl = j + 2 * i + half;
        idx[i] = (sl < deg) ? elist[base + sl] : esafe;
      }
      const float* p0 = ef + (size_t)idx[0] * DD + l32 * 4;
      const float* p1 = ef + (size_t)idx[1] * DD + l32 * 4;
      const float* p2 = ef + (size_t)idx[2] * DD + l32 * 4;
      const float* p3 = ef + (size_t)idx[3] * DD + l32 * 4;
      const float* p4 = ef + (size_t)idx[4] * DD + l32 * 4;
      const float* p5 = ef + (size_t)idx[5] * DD + l32 * 4;
      const float* p6 = ef + (size_t)idx[6] * DD + l32 * 4;
      const float* p7 = ef + (size_t)idx[7] * DD + l32 * 4;
      float4 m0, m1, m2, m3, m4, m5, m6, m7;
      asm volatile(
          "global_load_dwordx4 %0, %8, off\n\t"
          "global_load_dwordx4 %1, %9, off\n\t"
          "global_load_dwordx4 %2, %10, off\n\t"
          "global_load_dwordx4 %3, %11, off\n\t"
          "global_load_dwordx4 %4, %12, off\n\t"
          "global_load_dwordx4 %5, %13, off\n\t"
          "global_load_dwordx4 %6, %14, off\n\t"
          "global_load_dwordx4 %7, %15, off"
          : "=&v"(m0), "=&v"(m1), "=&v"(m2), "=&v"(m3),
            "=&v"(m4), "=&v"(m5), "=&v"(m6), "=&v"(m7)
          : "v"(p0), "v"(p1), "v"(p2), "v"(p3),
            "v"(p4), "v"(p5), "v"(p6), "v"(p7)
          : "memory");
      asm volatile("s_waitcnt vmcnt(0)" ::: "memory");
      __builtin_amdgcn_sched_barrier(0);
      #pragma unroll
      for (int i = 0; i < 8; ++i) {
        float4 m;
        switch (i) {
          case 0: m = m0; break; case 1: m = m1; break;
          case 2: m = m2; break; case 3: m = m3; break;
          case 4: m = m4; break; case 5: m = m5; break;
          case 6: m = m6; break; default: m = m7; break;
        }
        int sl = j + 2 * i + half;
        if (sl < deg) {
          acc[0] += fmaxf(m.x, 0.f);
          acc[1] += fmaxf(m.y, 0.f);
          acc[2] += fmaxf(m.z, 0.f);
          acc[3] += fmaxf(m.w, 0.f);
        }
      }
    }
  }
  float4 tot;
  tot.x = acc[0] + __shfl_xor(acc[0], 32);
  tot.y = acc[1] + __shfl_xor(acc[1], 32);
  tot.z = acc[2] + __shfl_xor(acc[2], 32);
  tot.w = acc[3] + __shfl_xor(acc[3], 32);
  if (half == 0)
    ((float4*)(nm + (size_t)v * DD))[l32] = tot;
}

// ---- W -> bf16 fragment-major precompute (once per launch) ----
// Wswz[((kt*8 + nt)*64 + lane)] (short8) = W[n = nt*16 + (lane&15)]
//                                           [k = kt*32 + (lane>>4)*8 .. +7]
__global__ __launch_bounds__(256) void wconv_kernel(
    const float* __restrict__ W, unsigned short* __restrict__ Wswz) {
  int idx = blockIdx.x * 256 + threadIdx.x;   // 2048 short8 fragments
  if (idx >= DD * DD / 8) return;
  int lane = idx & 63;
  int nt   = (idx >> 6) & 7;
  int kt   = idx >> 9;
  int n = nt * 16 + (lane & 15);
  int k = kt * 32 + (lane >> 4) * 8;
  const float4* wrow = (const float4*)(W + (size_t)n * DD + k);
  float4 w0 = wrow[0];
  float4 w1 = wrow[1];
  unsigned int p0 = f2bf(w0.x) | ((unsigned int)f2bf(w0.y) << 16);
  unsigned int p1 = f2bf(w0.z) | ((unsigned int)f2bf(w0.w) << 16);
  unsigned int p2 = f2bf(w1.x) | ((unsigned int)f2bf(w1.y) << 16);
  unsigned int p3 = f2bf(w1.z) | ((unsigned int)f2bf(w1.w) << 16);
  ((uint4*)Wswz)[idx] = make_uint4(p0, p1, p2, p3);
}

// ---- Phase C: out[e,:] = (nm[src[e],:] - relu(ef[rev[e],:])) @ W^T + b ----
// LDS-free. All 16 A-operand dwordx4 gathers live in ONE asm block — the
// compiler cannot re-serialize or shrink the landing zone (round-3 failure:
// VGPR=48 proved sched_barrier alone didn't hold). One vmcnt(0) wait, then
// cvt+MFMA. ~16 loads (2KB/lane-group) in flight per wave.
__global__ __launch_bounds__(256, 4) void fused_gather_gemm_kernel(
    const float* __restrict__ ef, const float* __restrict__ nm,
    const unsigned short* __restrict__ Wswz, const float* __restrict__ bias,
    const int* __restrict__ eidx, const int* __restrict__ rev,
    float* __restrict__ out, int E) {
  const int tid  = threadIdx.x;
  const int lane = tid & 63;
  const int wave = tid >> 6;                  // 4 waves, 16 edges each
  const int col  = lane & 15;
  const int quad = lane >> 4;
  const int e0   = blockIdx.x * TILE_E + wave * 16;

  const int ea = e0 + col;
  int s = 0, rv = 0;
  if (ea < E) { s = eidx[ea]; rv = rev[ea]; }
  // lane base: row + quad*8 floats (32B); kt stride = 128B, pair +16B
  const float* nb = nm + (size_t)s  * DD + quad * 8;
  const float* eb = ef + (size_t)rv * DD + quad * 8;
  const short8* __restrict__ wp = (const short8*)Wswz + lane;

  float4 a0, a1, a2, a3, a4, a5, a6, a7;
  float4 m0, m1, m2, m3, m4, m5, m6, m7;
  asm volatile(
      "global_load_dwordx4 %0, %16, off\n\t"
      "global_load_dwordx4 %1, %16, off offset:16\n\t"
      "global_load_dwordx4 %2, %17, off\n\t"
      "global_load_dwordx4 %3, %17, off offset:16\n\t"
      "global_load_dwordx4 %4, %16, off offset:128\n\t"
      "global_load_dwordx4 %5, %16, off offset:144\n\t"
      "global_load_dwordx4 %6, %17, off offset:128\n\t"
      "global_load_dwordx4 %7, %17, off offset:144\n\t"
      "global_load_dwordx4 %8, %16, off offset:256\n\t"
      "global_load_dwordx4 %9, %16, off offset:272\n\t"
      "global_load_dwordx4 %10, %17, off offset:256\n\t"
      "global_load_dwordx4 %11, %17, off offset:272\n\t"
      "global_load_dwordx4 %12, %16, off offset:384\n\t"
      "global_load_dwordx4 %13, %16, off offset:400\n\t"
      "global_load_dwordx4 %14, %17, off offset:384\n\t"
      "global_load_dwordx4 %15, %17, off offset:400"
      : "=&v"(a0), "=&v"(a1), "=&v"(m0), "=&v"(m1),
        "=&v"(a2), "=&v"(a3), "=&v"(m2), "=&v"(m3),
        "=&v"(a4), "=&v"(a5), "=&v"(m4), "=&v"(m5),
        "=&v"(a6), "=&v"(a7), "=&v"(m6), "=&v"(m7)
      : "v"(nb), "v"(eb)
      : "memory");
  asm volatile("s_waitcnt vmcnt(0)" ::: "memory");
  __builtin_amdgcn_sched_barrier(0);

  f32x4 acc[8];
  #pragma unroll
  for (int i = 0; i < 8; ++i) acc[i] = (f32x4){0.f, 0.f, 0.f, 0.f};

  #pragma unroll
  for (int kt = 0; kt < 4; ++kt) {
    float4 va0, va1, vm0, vm1;
    switch (kt) {
      case 0:  va0 = a0; va1 = a1; vm0 = m0; vm1 = m1; break;
      case 1:  va0 = a2; va1 = a3; vm0 = m2; vm1 = m3; break;
      case 2:  va0 = a4; va1 = a5; vm0 = m4; vm1 = m5; break;
      default: va0 = a6; va1 = a7; vm0 = m6; vm1 = m7; break;
    }
    float x0 = va0.x - fmaxf(vm0.x, 0.f);
    float x1 = va0.y - fmaxf(vm0.y, 0.f);
    float x2 = va0.z - fmaxf(vm0.z, 0.f);
    float x3 = va0.w - fmaxf(vm0.w, 0.f);
    float x4 = va1.x - fmaxf(vm1.x, 0.f);
    float x5 = va1.y - fmaxf(vm1.y, 0.f);
    float x6 = va1.z - fmaxf(vm1.z, 0.f);
    float x7 = va1.w - fmaxf(vm1.w, 0.f);
    union { unsigned int u[4]; short8 s8; } cvt;
    cvt.u[0] = f2bf(x0) | ((unsigned int)f2bf(x1) << 16);
    cvt.u[1] = f2bf(x2) | ((unsigned int)f2bf(x3) << 16);
    cvt.u[2] = f2bf(x4) | ((unsigned int)f2bf(x5) << 16);
    cvt.u[3] = f2bf(x6) | ((unsigned int)f2bf(x7) << 16);
    short8 av = cvt.s8;
    #pragma unroll
    for (int nt = 0; nt < 8; ++nt) {
      short8 b = wp[(kt * 8 + nt) * 64];
      acc[nt] = __builtin_amdgcn_mfma_f32_16x16x32_bf16(av, b, acc[nt], 0, 0, 0);
    }
  }

  // epilogue: D[row=quad*4+r][col], +bias; non-temporal (out never re-read)
  #pragma unroll
  for (int nt = 0; nt < 8; ++nt) {
    float bj = bias[nt * 16 + col];
    #pragma unroll
    for (int r = 0; r < 4; ++r) {
      int e = e0 + quad * 4 + r;
      if (e < E)
        __builtin_nontemporal_store(acc[nt][r] + bj,
                                    &out[(size_t)e * DD + nt * 16 + col]);
    }
  }
}

extern "C" void kernel_launch(void* const* d_in, const int* in_sizes, int n_in,
                              void* d_out, int out_size, void* d_ws, size_t ws_size,
                              hipStream_t stream) {
  const float* ef   = (const float*)d_in[0];
  const float* W    = (const float*)d_in[2];
  const float* bias = (const float*)d_in[3];
  const int*   eidx = (const int*)d_in[4];   // [2,E]: row0=src, row1=dest (int32 per harness)
  const int*   rev  = (const int*)d_in[5];   // [E]
  float*       out  = (float*)d_out;

  const int V = in_sizes[1];
  const int E = in_sizes[5];

  // workspace layout (256B-aligned slices)
  char* ws = (char*)d_ws;
  size_t o = 0;
  float* nm = (float*)(ws + o);            o += (size_t)V * DD * sizeof(float);
  o = (o + 255) & ~(size_t)255;
  int* cnt  = (int*)(ws + o);              o += (size_t)V * sizeof(int);
  o = (o + 255) & ~(size_t)255;
  int* off  = (int*)(ws + o);              o += (size_t)V * sizeof(int);
  o = (o + 255) & ~(size_t)255;
  int* cur  = (int*)(ws + o);              o += (size_t)V * sizeof(int);
  o = (o + 255) & ~(size_t)255;
  int* elist = (int*)(ws + o);             o += (size_t)E * sizeof(int);
  o = (o + 255) & ~(size_t)255;
  unsigned short* Wswz = (unsigned short*)(ws + o);

  hipMemsetAsync(cnt, 0, (size_t)V * sizeof(int), stream);

  int eb = (E + 255) / 256;
  hist_kernel<<<eb, 256, 0, stream>>>(eidx, cnt, E);
  scan_kernel<<<1, 1024, 0, stream>>>(cnt, off, cur, V);
  fill_kernel<<<eb, 256, 0, stream>>>(eidx, cur, elist, E);
  gather_sum_kernel<<<(V + 3) / 4, 256, 0, stream>>>(ef, off, cnt, elist, nm, V);
  wconv_kernel<<<(DD * DD / 8 + 255) / 256, 256, 0, stream>>>(W, Wswz);

  int nblocks = (E + TILE_E - 1) / TILE_E;
  fused_gather_gemm_kernel<<<nblocks, 256, 0, stream>>>(ef, nm, Wswz, bias, eidx, rev, out, E);
}

// Round 5
// 667.044 us; speedup vs baseline: 1.0705x; 1.0705x over previous
//
#include <hip/hip_runtime.h>

#define DD 128
#define TILE_E 64

typedef __attribute__((ext_vector_type(8))) short short8;
typedef __attribute__((ext_vector_type(4))) float f32x4;

__device__ __forceinline__ unsigned short f2bf(float f) {
  unsigned int u = __float_as_uint(f);
  u += 0x7FFF + ((u >> 16) & 1);   // RNE
  return (unsigned short)(u >> 16);
}

// ---- Phase A: build dest-sorted edge list (replaces 64M fp32 atomics) ----

__global__ __launch_bounds__(256) void hist_kernel(
    const int* __restrict__ eidx, int* __restrict__ cnt, int E) {
  int e = blockIdx.x * 256 + threadIdx.x;
  if (e < E) atomicAdd(&cnt[eidx[E + e]], 1);
}

// single-block tiled scan, coalesced loads/stores, shfl-based (4 barriers/tile)
// (old version did per-thread sequential 49-element chunks -> uncoalesced serial
// loops on one CU)
__global__ __launch_bounds__(1024) void scan_kernel(
    const int* __restrict__ cnt, int* __restrict__ off, int* __restrict__ cur, int V) {
  __shared__ int wsum[16];
  __shared__ int woff[16];
  __shared__ int carry;
  const int t    = threadIdx.x;
  const int lane = t & 63;
  const int wid  = t >> 6;
  if (t == 0) carry = 0;
  __syncthreads();
  for (int base = 0; base < V; base += 1024) {
    int i = base + t;
    int x = (i < V) ? cnt[i] : 0;
    // wave-inclusive scan
    int v = x;
    #pragma unroll
    for (int d = 1; d < 64; d <<= 1) {
      int y = __shfl_up(v, d);
      if (lane >= d) v += y;
    }
    if (lane == 63) wsum[wid] = v;
    __syncthreads();
    if (wid == 0) {
      int wv = (lane < 16) ? wsum[lane] : 0;
      #pragma unroll
      for (int d = 1; d < 16; d <<= 1) {
        int y = __shfl_up(wv, d);
        if (lane >= d) wv += y;
      }
      if (lane < 16) woff[lane] = wv;   // inclusive wave-sum scan
    }
    __syncthreads();
    int wexcl = (wid > 0) ? woff[wid - 1] : 0;
    int excl  = carry + wexcl + v - x;
    if (i < V) { off[i] = excl; cur[i] = excl; }
    int tot = woff[15];
    __syncthreads();
    if (t == 0) carry += tot;
    __syncthreads();
  }
}

__global__ __launch_bounds__(256) void fill_kernel(
    const int* __restrict__ eidx, int* __restrict__ cur,
    int* __restrict__ elist, int E) {
  int e = blockIdx.x * 256 + threadIdx.x;
  if (e < E) {
    int p = atomicAdd(&cur[eidx[E + e]], 1);
    elist[p] = e;
  }
}

// ---- Phase B: nm[v,:] = sum relu(ef[e,:]); ALSO emits mbf[e,:] = bf16(relu) ----
// Each edge row is touched exactly once across all nodes, so the bf16 message
// tensor (128 MB, L3-resident afterwards) is produced for free off the same
// f32 loads. nm accumulates from f32 (precision unchanged).
__global__ __launch_bounds__(256) void gather_sum_kernel(
    const float* __restrict__ ef, const int* __restrict__ off,
    const int* __restrict__ cnt, const int* __restrict__ elist,
    float* __restrict__ nm, unsigned short* __restrict__ mbf, int V) {
  const int lane = threadIdx.x & 63;
  const int half = lane >> 5;        // 0: even slots, 1: odd slots
  const int l32  = lane & 31;        // float4 index within row
  const int v = blockIdx.x * 4 + (threadIdx.x >> 6);
  if (v >= V) return;
  const int base = off[v];
  const int deg  = cnt[v];
  f32x4 acc = (f32x4){0.f, 0.f, 0.f, 0.f};
  if (deg > 0) {
    const int esafe = elist[base];
    for (int j = 0; j < deg; j += 16) {
      int idx[8];
      #pragma unroll
      for (int i = 0; i < 8; ++i) {
        int sl = j + 2 * i + half;
        idx[i] = (sl < deg) ? elist[base + sl] : esafe;
      }
      const float* p0 = ef + (size_t)idx[0] * DD + l32 * 4;
      const float* p1 = ef + (size_t)idx[1] * DD + l32 * 4;
      const float* p2 = ef + (size_t)idx[2] * DD + l32 * 4;
      const float* p3 = ef + (size_t)idx[3] * DD + l32 * 4;
      const float* p4 = ef + (size_t)idx[4] * DD + l32 * 4;
      const float* p5 = ef + (size_t)idx[5] * DD + l32 * 4;
      const float* p6 = ef + (size_t)idx[6] * DD + l32 * 4;
      const float* p7 = ef + (size_t)idx[7] * DD + l32 * 4;
      float4 m0, m1, m2, m3, m4, m5, m6, m7;
      asm volatile(
          "global_load_dwordx4 %0, %8, off\n\t"
          "global_load_dwordx4 %1, %9, off\n\t"
          "global_load_dwordx4 %2, %10, off\n\t"
          "global_load_dwordx4 %3, %11, off\n\t"
          "global_load_dwordx4 %4, %12, off\n\t"
          "global_load_dwordx4 %5, %13, off\n\t"
          "global_load_dwordx4 %6, %14, off\n\t"
          "global_load_dwordx4 %7, %15, off"
          : "=&v"(m0), "=&v"(m1), "=&v"(m2), "=&v"(m3),
            "=&v"(m4), "=&v"(m5), "=&v"(m6), "=&v"(m7)
          : "v"(p0), "v"(p1), "v"(p2), "v"(p3),
            "v"(p4), "v"(p5), "v"(p6), "v"(p7)
          : "memory");
      asm volatile("s_waitcnt vmcnt(0)" ::: "memory");
      __builtin_amdgcn_sched_barrier(0);
      #pragma unroll
      for (int i = 0; i < 8; ++i) {
        float4 m;
        switch (i) {
          case 0: m = m0; break; case 1: m = m1; break;
          case 2: m = m2; break; case 3: m = m3; break;
          case 4: m = m4; break; case 5: m = m5; break;
          case 6: m = m6; break; default: m = m7; break;
        }
        int sl = j + 2 * i + half;
        if (sl < deg) {
          float r0 = fmaxf(m.x, 0.f);
          float r1 = fmaxf(m.y, 0.f);
          float r2 = fmaxf(m.z, 0.f);
          float r3 = fmaxf(m.w, 0.f);
          acc[0] += r0; acc[1] += r1; acc[2] += r2; acc[3] += r3;
          uint2 pk;
          pk.x = f2bf(r0) | ((unsigned int)f2bf(r1) << 16);
          pk.y = f2bf(r2) | ((unsigned int)f2bf(r3) << 16);
          *(uint2*)(mbf + (size_t)idx[i] * DD + l32 * 4) = pk;
        }
      }
    }
  }
  float4 tot;
  tot.x = acc[0] + __shfl_xor(acc[0], 32);
  tot.y = acc[1] + __shfl_xor(acc[1], 32);
  tot.z = acc[2] + __shfl_xor(acc[2], 32);
  tot.w = acc[3] + __shfl_xor(acc[3], 32);
  if (half == 0)
    ((float4*)(nm + (size_t)v * DD))[l32] = tot;
}

// ---- W -> bf16 fragment-major precompute (once per launch) ----
// Wswz[((kt*8 + nt)*64 + lane)] (short8) = W[n = nt*16 + (lane&15)]
//                                           [k = kt*32 + (lane>>4)*8 .. +7]
__global__ __launch_bounds__(256) void wconv_kernel(
    const float* __restrict__ W, unsigned short* __restrict__ Wswz) {
  int idx = blockIdx.x * 256 + threadIdx.x;   // 2048 short8 fragments
  if (idx >= DD * DD / 8) return;
  int lane = idx & 63;
  int nt   = (idx >> 6) & 7;
  int kt   = idx >> 9;
  int n = nt * 16 + (lane & 15);
  int k = kt * 32 + (lane >> 4) * 8;
  const float4* wrow = (const float4*)(W + (size_t)n * DD + k);
  float4 w0 = wrow[0];
  float4 w1 = wrow[1];
  unsigned int p0 = f2bf(w0.x) | ((unsigned int)f2bf(w0.y) << 16);
  unsigned int p1 = f2bf(w0.z) | ((unsigned int)f2bf(w0.w) << 16);
  unsigned int p2 = f2bf(w1.x) | ((unsigned int)f2bf(w1.y) << 16);
  unsigned int p3 = f2bf(w1.z) | ((unsigned int)f2bf(w1.w) << 16);
  ((uint4*)Wswz)[idx] = make_uint4(p0, p1, p2, p3);
}

// ---- Phase C: out[e,:] = (nm[src[e],:] - mbf[rev[e],:]) @ W^T + b ----
// Random reads now hit L3: nm (25.6 MB) + mbf (128 MB, just written) both fit
// in the 256 MB Infinity Cache. mbf rows are 256 B (bf16) -> half the random
// bytes of round 4. 12-load prefetch (8 nm + 4 mbf) pinned by sched_barrier.
__global__ __launch_bounds__(256, 4) void fused_gather_gemm_kernel(
    const float* __restrict__ nm, const unsigned short* __restrict__ mbf,
    const unsigned short* __restrict__ Wswz, const float* __restrict__ bias,
    const int* __restrict__ eidx, const int* __restrict__ rev,
    float* __restrict__ out, int E) {
  const int tid  = threadIdx.x;
  const int lane = tid & 63;
  const int wave = tid >> 6;                  // 4 waves, 16 edges each
  const int col  = lane & 15;
  const int quad = lane >> 4;
  const int e0   = blockIdx.x * TILE_E + wave * 16;

  const int ea = e0 + col;
  int s = 0, rv = 0;
  if (ea < E) { s = eidx[ea]; rv = rev[ea]; }
  const float4* __restrict__ nmp = (const float4*)(nm + (size_t)s * DD);
  const uint4*  __restrict__ mp  = (const uint4*)(mbf + (size_t)rv * DD);

  const short8* __restrict__ wp = (const short8*)Wswz + lane;

  // prefetch: per kt, 2 nm float4s + 1 mbf uint4 (16B = 8 bf16)
  float4 a[8];
  uint4  mm[4];
  #pragma unroll
  for (int kt = 0; kt < 4; ++kt) {
    const int k4 = kt * 8 + quad * 2;         // nm float4 index: k = kt*32+quad*8
    a[kt * 2]     = nmp[k4];
    a[kt * 2 + 1] = nmp[k4 + 1];
    mm[kt]        = mp[kt * 4 + quad];        // bf16 elems kt*32+quad*8 .. +7
  }
  __builtin_amdgcn_sched_barrier(0);          // loads may NOT sink past here

  f32x4 acc[8];
  #pragma unroll
  for (int i = 0; i < 8; ++i) acc[i] = (f32x4){0.f, 0.f, 0.f, 0.f};

  #pragma unroll
  for (int kt = 0; kt < 4; ++kt) {
    float4 a0 = a[kt * 2], a1 = a[kt * 2 + 1];
    uint4  u  = mm[kt];
    float x0 = a0.x - __uint_as_float(u.x << 16);
    float x1 = a0.y - __uint_as_float(u.x & 0xFFFF0000u);
    float x2 = a0.z - __uint_as_float(u.y << 16);
    float x3 = a0.w - __uint_as_float(u.y & 0xFFFF0000u);
    float x4 = a1.x - __uint_as_float(u.z << 16);
    float x5 = a1.y - __uint_as_float(u.z & 0xFFFF0000u);
    float x6 = a1.z - __uint_as_float(u.w << 16);
    float x7 = a1.w - __uint_as_float(u.w & 0xFFFF0000u);
    union { unsigned int uu[4]; short8 s8; } cvt;
    cvt.uu[0] = f2bf(x0) | ((unsigned int)f2bf(x1) << 16);
    cvt.uu[1] = f2bf(x2) | ((unsigned int)f2bf(x3) << 16);
    cvt.uu[2] = f2bf(x4) | ((unsigned int)f2bf(x5) << 16);
    cvt.uu[3] = f2bf(x6) | ((unsigned int)f2bf(x7) << 16);
    short8 av = cvt.s8;
    #pragma unroll
    for (int nt = 0; nt < 8; ++nt) {
      short8 b = wp[(kt * 8 + nt) * 64];
      acc[nt] = __builtin_amdgcn_mfma_f32_16x16x32_bf16(av, b, acc[nt], 0, 0, 0);
    }
  }

  // epilogue: D[row=quad*4+r][col], +bias; non-temporal (out never re-read)
  #pragma unroll
  for (int nt = 0; nt < 8; ++nt) {
    float bj = bias[nt * 16 + col];
    #pragma unroll
    for (int r = 0; r < 4; ++r) {
      int e = e0 + quad * 4 + r;
      if (e < E)
        __builtin_nontemporal_store(acc[nt][r] + bj,
                                    &out[(size_t)e * DD + nt * 16 + col]);
    }
  }
}

extern "C" void kernel_launch(void* const* d_in, const int* in_sizes, int n_in,
                              void* d_out, int out_size, void* d_ws, size_t ws_size,
                              hipStream_t stream) {
  const float* ef   = (const float*)d_in[0];
  const float* W    = (const float*)d_in[2];
  const float* bias = (const float*)d_in[3];
  const int*   eidx = (const int*)d_in[4];   // [2,E]: row0=src, row1=dest (int32 per harness)
  const int*   rev  = (const int*)d_in[5];   // [E]
  float*       out  = (float*)d_out;

  const int V = in_sizes[1];
  const int E = in_sizes[5];

  // workspace layout (256B-aligned slices)
  char* ws = (char*)d_ws;
  size_t o = 0;
  float* nm = (float*)(ws + o);            o += (size_t)V * DD * sizeof(float);
  o = (o + 255) & ~(size_t)255;
  int* cnt  = (int*)(ws + o);              o += (size_t)V * sizeof(int);
  o = (o + 255) & ~(size_t)255;
  int* off  = (int*)(ws + o);              o += (size_t)V * sizeof(int);
  o = (o + 255) & ~(size_t)255;
  int* cur  = (int*)(ws + o);              o += (size_t)V * sizeof(int);
  o = (o + 255) & ~(size_t)255;
  int* elist = (int*)(ws + o);             o += (size_t)E * sizeof(int);
  o = (o + 255) & ~(size_t)255;
  unsigned short* Wswz = (unsigned short*)(ws + o);
  o += (size_t)DD * DD * sizeof(unsigned short);
  o = (o + 255) & ~(size_t)255;
  unsigned short* mbf = (unsigned short*)(ws + o);   // [E, DD] bf16 = 128 MB

  hipMemsetAsync(cnt, 0, (size_t)V * sizeof(int), stream);

  int eb = (E + 255) / 256;
  hist_kernel<<<eb, 256, 0, stream>>>(eidx, cnt, E);
  scan_kernel<<<1, 1024, 0, stream>>>(cnt, off, cur, V);
  fill_kernel<<<eb, 256, 0, stream>>>(eidx, cur, elist, E);
  gather_sum_kernel<<<(V + 3) / 4, 256, 0, stream>>>(ef, off, cnt, elist, nm, mbf, V);
  wconv_kernel<<<(DD * DD / 8 + 255) / 256, 256, 0, stream>>>(W, Wswz);

  int nblocks = (E + TILE_E - 1) / TILE_E;
  fused_gather_gemm_kernel<<<nblocks, 256, 0, stream>>>(nm, mbf, Wswz, bias, eidx, rev, out, E);
}